// Round 1
// baseline (474.638 us; speedup 1.0000x reference)
//
#include <hip/hip_runtime.h>

#define KCLS 19
#define NIMG 4
#define CCH  128
#define PPIX (256*512)   // 131072 pixels per image
#define CG   2           // channels per k_sums block

// ---------------- workspace layout (floats) ----------------
// sums     [N][K][C]  @ 0        (9728)   zeroed
// counts   [N][K]     @ 9728     (76)     zeroed
// per_cls  [N][K]     @ 9804     (76)     zeroed
// means    [N][K][C]  @ 9880     (9728)
// validf   [N][K]     @ 19608    (76)
// nvArr    [N]        @ 19684    (4)
// imgPart  [N]        @ 19688    (4)

// ---------- kernel 0: per-class pixel counts ----------
__global__ __launch_bounds__(256) void k_counts(const int* __restrict__ target,
                                                float* __restrict__ counts) {
  __shared__ int lcnt[KCLS];
  const int tid = threadIdx.x;
  if (tid < KCLS) lcnt[tid] = 0;
  __syncthreads();
  const int n = blockIdx.x >> 7;          // 128 blocks per image
  const int tile = blockIdx.x & 127;
  const int4 lb = *(const int4*)(target + (size_t)n*PPIX + tile*1024 + tid*4);
  const int kk[4] = {lb.x, lb.y, lb.z, lb.w};
#pragma unroll
  for (int j = 0; j < 4; ++j) {
    unsigned k = (unsigned)kk[j];
    if (k < KCLS) atomicAdd(&lcnt[k], 1);
  }
  __syncthreads();
  if (tid < KCLS && lcnt[tid] > 0)
    atomicAdd(&counts[n*KCLS + tid], (float)lcnt[tid]);
}

// ---------- kernel 1: per-class feature sums (segment-sum) ----------
// block = (image n, channel pair c0..c0+1, pixel half). Per-thread private
// LDS columns: cols[k][tid] is a float2 (one lane-exclusive accumulator per
// class per thread; bank = tid%32 -> free 2-way aliasing, no atomics needed).
__global__ __launch_bounds__(256) void k_sums(const float* __restrict__ predict,
                                              const int* __restrict__ target,
                                              float* __restrict__ sums) {
  __shared__ float2 cols[KCLS*256];   // 38912 B
  const int tid = threadIdx.x;
  const int n    = blockIdx.x >> 7;
  const int rem  = blockIdx.x & 127;
  const int cg   = rem >> 1;
  const int half = rem & 1;
  const int c0   = cg * CG;

  for (int i = tid; i < KCLS*256; i += 256) cols[i] = make_float2(0.f, 0.f);
  __syncthreads();

  const float* p0 = predict + ((size_t)n*CCH + c0) * PPIX;
  const float* p1 = p0 + PPIX;
  const int*  lab = target + (size_t)n*PPIX;
  const int base0 = half * (PPIX/2);

  for (int off = tid*4; off < PPIX/2; off += 1024) {   // 64 iters
    const int base = base0 + off;
    const int4   lb = *(const int4*)(lab + base);
    const float4 a  = *(const float4*)(p0 + base);
    const float4 b  = *(const float4*)(p1 + base);
    const int   kk[4] = {lb.x, lb.y, lb.z, lb.w};
    const float av[4] = {a.x, a.y, a.z, a.w};
    const float bv[4] = {b.x, b.y, b.z, b.w};
#pragma unroll
    for (int j = 0; j < 4; ++j) {
      unsigned k = (unsigned)kk[j];
      if (k < KCLS) {
        float2* cp = &cols[k*256 + tid];
        cp->x += av[j];
        cp->y += bv[j];
      }
    }
  }
  __syncthreads();
  // tree-reduce the 256 columns for all 19 classes
  for (int s = 128; s >= 1; s >>= 1) {
    if (tid < s) {
#pragma unroll
      for (int r = 0; r < KCLS; ++r) {
        cols[r*256 + tid].x += cols[r*256 + tid + s].x;
        cols[r*256 + tid].y += cols[r*256 + tid + s].y;
      }
    }
    __syncthreads();
  }
  if (tid < KCLS) {
    atomicAdd(&sums[((size_t)n*KCLS + tid)*CCH + c0    ], cols[tid*256].x);
    atomicAdd(&sums[((size_t)n*KCLS + tid)*CCH + c0 + 1], cols[tid*256].y);
  }
}

// ---------- kernel 2: means, valid, nv, loss_dis + 0.001*loss_reg ----------
__global__ __launch_bounds__(256) void k_stats(const float* __restrict__ sums,
                                               const float* __restrict__ counts,
                                               float* __restrict__ means,
                                               float* __restrict__ validf,
                                               float* __restrict__ nvArr,
                                               float* __restrict__ imgPart) {
  __shared__ float ml[KCLS*129];   // padded [k][c], stride 129 -> conflict-free lane-varying k
  __shared__ float sval[KCLS];
  __shared__ float red[256];
  __shared__ float nvs;
  const int tid = threadIdx.x;

  for (int i = tid; i < NIMG*KCLS*CCH; i += 256) {
    const int nk = i / CCH;
    means[i] = sums[i] / fmaxf(counts[nk], 1.f);
  }
  __syncthreads();   // block-level fence: means visible for re-read

  for (int n = 0; n < NIMG; ++n) {
    for (int i = tid; i < KCLS*CCH; i += 256) {
      const int k = i >> 7, c = i & 127;
      ml[k*129 + c] = means[n*KCLS*CCH + i];
    }
    if (tid < KCLS) sval[tid] = (counts[n*KCLS + tid] > 20.f) ? 1.f : 0.f;
    __syncthreads();
    if (tid == 0) {
      float s = 0.f;
      for (int k = 0; k < KCLS; ++k) s += sval[k];
      nvs = fmaxf(s, 1.f);
      nvArr[n] = nvs;
    }
    if (tid < KCLS) validf[n*KCLS + tid] = sval[tid];
    __syncthreads();

    // loss_dis: ordered pairs f != s, both valid
    float local = 0.f;
    for (int pr = tid; pr < KCLS*KCLS; pr += 256) {
      const int f = pr / KCLS, s2 = pr % KCLS;
      if (f != s2 && sval[f] > 0.f && sval[s2] > 0.f) {
        float acc = 0.f;
        for (int c = 0; c < CCH; ++c) {
          const float d = ml[f*129 + c] - ml[s2*129 + c];
          acc = fmaf(d, d, acc);
        }
        const float t = fmaxf(3.0f - sqrtf(acc), 0.f);   // 2*DELTA = 3
        local += t * t;
      }
    }
    // loss_reg: center norms of valid classes
    float localReg = 0.f;
    if (tid < KCLS && sval[tid] > 0.f) {
      float acc = 0.f;
      for (int c = 0; c < CCH; ++c) {
        const float m = ml[tid*129 + c];
        acc = fmaf(m, m, acc);
      }
      localReg = sqrtf(acc);
    }
    red[tid] = local;
    __syncthreads();
    for (int s3 = 128; s3 >= 1; s3 >>= 1) {
      if (tid < s3) red[tid] += red[tid + s3];
      __syncthreads();
    }
    const float disSum = red[0];
    __syncthreads();
    red[tid] = localReg;
    __syncthreads();
    for (int s3 = 128; s3 >= 1; s3 >>= 1) {
      if (tid < s3) red[tid] += red[tid + s3];
      __syncthreads();
    }
    if (tid == 0) {
      const float nv = nvs;
      const float dis = disSum / fmaxf(nv*(nv - 1.f), 1.f);
      const float reg = red[0] / nv;
      imgPart[n] = dis + 0.001f * reg;
    }
    __syncthreads();
  }
}

// ---------- kernel 3: loss_var pass (second full read of predict) ----------
// thread = 4 consecutive pixels; c-loop reads lane-contiguous float4 (coalesced).
// means transposed in LDS as [c][k] with stride 20: per-c class-indexed reads
// land on 19 distinct banks -> conflict-free.
__global__ __launch_bounds__(256) void k_var(const float* __restrict__ predict,
                                             const int* __restrict__ target,
                                             const float* __restrict__ means,
                                             float* __restrict__ per_cls) {
  __shared__ float mT[CCH*20];   // 10240 B
  __shared__ float pc[KCLS];
  const int tid = threadIdx.x;
  const int n = blockIdx.x >> 7;
  const int tile = blockIdx.x & 127;

  for (int i = tid; i < KCLS*CCH; i += 256) {
    const int k = i >> 7, c = i & 127;
    mT[c*20 + k] = means[n*KCLS*CCH + i];
  }
  if (tid < KCLS) pc[tid] = 0.f;

  const int p0 = tile*1024 + tid*4;
  const int4 lb = *(const int4*)(target + (size_t)n*PPIX + p0);
  const unsigned u0 = min((unsigned)lb.x, (unsigned)(KCLS-1));
  const unsigned u1 = min((unsigned)lb.y, (unsigned)(KCLS-1));
  const unsigned u2 = min((unsigned)lb.z, (unsigned)(KCLS-1));
  const unsigned u3 = min((unsigned)lb.w, (unsigned)(KCLS-1));
  __syncthreads();

  float acc0 = 0.f, acc1 = 0.f, acc2 = 0.f, acc3 = 0.f;
  const float* gp = predict + (size_t)n*CCH*PPIX + p0;
#pragma unroll 8
  for (int c = 0; c < CCH; ++c) {
    const float4 v = *(const float4*)gp;
    gp += PPIX;
    const float* row = mT + c*20;
    const float d0 = row[u0] - v.x; acc0 = fmaf(d0, d0, acc0);
    const float d1 = row[u1] - v.y; acc1 = fmaf(d1, d1, acc1);
    const float d2 = row[u2] - v.z; acc2 = fmaf(d2, d2, acc2);
    const float d3 = row[u3] - v.w; acc3 = fmaf(d3, d3, acc3);
  }
  // r = relu(sqrt(acc) - 0.5)^2, accumulated per class
  {
    float t;
    t = fmaxf(sqrtf(acc0) - 0.5f, 0.f); if ((unsigned)lb.x < KCLS) atomicAdd(&pc[lb.x], t*t);
    t = fmaxf(sqrtf(acc1) - 0.5f, 0.f); if ((unsigned)lb.y < KCLS) atomicAdd(&pc[lb.y], t*t);
    t = fmaxf(sqrtf(acc2) - 0.5f, 0.f); if ((unsigned)lb.z < KCLS) atomicAdd(&pc[lb.z], t*t);
    t = fmaxf(sqrtf(acc3) - 0.5f, 0.f); if ((unsigned)lb.w < KCLS) atomicAdd(&pc[lb.w], t*t);
  }
  __syncthreads();
  if (tid < KCLS) atomicAdd(&per_cls[n*KCLS + tid], pc[tid]);
}

// ---------- kernel 4: combine ----------
__global__ __launch_bounds__(128) void k_final(const float* __restrict__ per_cls,
                                               const float* __restrict__ counts,
                                               const float* __restrict__ validf,
                                               const float* __restrict__ nvArr,
                                               const float* __restrict__ imgPart,
                                               float* __restrict__ out) {
  __shared__ float red[128];
  const int tid = threadIdx.x;
  float local = 0.f;
  if (tid < NIMG*KCLS) {
    const int n = tid / KCLS;
    local = validf[tid] * (per_cls[tid] / fmaxf(counts[tid], 1.f)) / nvArr[n];
  } else if (tid < NIMG*KCLS + NIMG) {
    local = imgPart[tid - NIMG*KCLS];
  }
  red[tid] = local;
  __syncthreads();
  for (int s = 64; s >= 1; s >>= 1) {
    if (tid < s) red[tid] += red[tid + s];
    __syncthreads();
  }
  if (tid == 0) out[0] = 0.25f * red[0];   // mean over NIMG=4
}

extern "C" void kernel_launch(void* const* d_in, const int* in_sizes, int n_in,
                              void* d_out, int out_size, void* d_ws, size_t ws_size,
                              hipStream_t stream) {
  const float* predict = (const float*)d_in[0];
  const int*   target  = (const int*)d_in[1];
  float* out = (float*)d_out;
  float* ws  = (float*)d_ws;

  float* sums    = ws;            // 9728
  float* counts  = ws + 9728;     // 76
  float* per_cls = ws + 9804;     // 76
  float* means   = ws + 9880;     // 9728
  float* validf  = ws + 19608;    // 76
  float* nvArr   = ws + 19684;    // 4
  float* imgPart = ws + 19688;    // 4

  // zero the accumulator region (sums + counts + per_cls); ws is poisoned 0xAA
  hipMemsetAsync(ws, 0, (size_t)9880 * sizeof(float), stream);

  k_counts<<<NIMG*128, 256, 0, stream>>>(target, counts);
  k_sums  <<<NIMG*(CCH/CG)*2, 256, 0, stream>>>(predict, target, sums);
  k_stats <<<1, 256, 0, stream>>>(sums, counts, means, validf, nvArr, imgPart);
  k_var   <<<NIMG*128, 256, 0, stream>>>(predict, target, means, per_cls);
  k_final <<<1, 128, 0, stream>>>(per_cls, counts, validf, nvArr, imgPart, out);
}

// Round 2
// 432.810 us; speedup vs baseline: 1.0966x; 1.0966x over previous
//
#include <hip/hip_runtime.h>

#define KCLS 19
#define NIMG 4
#define CCH  128
#define PPIX (256*512)   // 131072 pixels per image

// ---------------- workspace layout (floats) ----------------
// sums     [N][K][C]  @ 0        (9728)   zeroed
// counts   [N][K]     @ 9728     (76)     zeroed
// per_cls  [N][K]     @ 9804     (76)     zeroed
// means    [N][K][C]  @ 9880     (9728)
// validf   [N][K]     @ 19608    (76)
// nvArr    [N]        @ 19684    (4)
// imgPart  [N]        @ 19688    (4)

// ---------- kernel 1: per-class feature sums + counts (fused) ----------
// block = (image n, channel pair c0..c0+1, pixel half). Per-thread private
// LDS columns: cols[k][tid] is a float2 (lane-exclusive accumulator per
// class per thread; bank = 2*tid%32 -> b64 access at the 4-cycle minimum,
// no atomics). cg==0 blocks additionally histogram the labels (they cover
// every pixel exactly once across images/halves).
__global__ __launch_bounds__(256) void k_sums(const float* __restrict__ predict,
                                              const int* __restrict__ target,
                                              float* __restrict__ sums,
                                              float* __restrict__ counts) {
  __shared__ float2 cols[KCLS*256];   // 38912 B -> 2 blocks/CU by LDS
  __shared__ int lcnt[KCLS];
  const int tid = threadIdx.x;
  const int n    = blockIdx.x >> 7;
  const int rem  = blockIdx.x & 127;
  const int cg   = rem >> 1;
  const int half = rem & 1;
  const int c0   = cg * 2;
  const bool doCount = (cg == 0);

  for (int i = tid; i < KCLS*256; i += 256) cols[i] = make_float2(0.f, 0.f);
  if (tid < KCLS) lcnt[tid] = 0;
  __syncthreads();

  const float* p0 = predict + ((size_t)n*CCH + c0) * PPIX;
  const float* p1 = p0 + PPIX;
  const int*  lab = target + (size_t)n*PPIX;
  const int base0 = half * (PPIX/2);

  for (int off = tid*4; off < PPIX/2; off += 1024) {   // 64 iters
    const int base = base0 + off;
    const int4   lb = *(const int4*)(lab + base);
    const float4 a  = *(const float4*)(p0 + base);
    const float4 b  = *(const float4*)(p1 + base);
    const int   kk[4] = {lb.x, lb.y, lb.z, lb.w};
    const float av[4] = {a.x, a.y, a.z, a.w};
    const float bv[4] = {b.x, b.y, b.z, b.w};
#pragma unroll
    for (int j = 0; j < 4; ++j) {
      unsigned k = (unsigned)kk[j];
      if (k < KCLS) {
        float2* cp = &cols[k*256 + tid];
        cp->x += av[j];
        cp->y += bv[j];
        if (doCount) atomicAdd(&lcnt[k], 1);   // block-uniform branch
      }
    }
  }
  __syncthreads();
  // tree-reduce the 256 columns for all 19 classes
  for (int s = 128; s >= 1; s >>= 1) {
    if (tid < s) {
#pragma unroll
      for (int r = 0; r < KCLS; ++r) {
        cols[r*256 + tid].x += cols[r*256 + tid + s].x;
        cols[r*256 + tid].y += cols[r*256 + tid + s].y;
      }
    }
    __syncthreads();
  }
  if (tid < KCLS) {
    atomicAdd(&sums[((size_t)n*KCLS + tid)*CCH + c0    ], cols[tid*256].x);
    atomicAdd(&sums[((size_t)n*KCLS + tid)*CCH + c0 + 1], cols[tid*256].y);
    if (doCount && lcnt[tid] > 0)
      atomicAdd(&counts[n*KCLS + tid], (float)lcnt[tid]);
  }
}

// ---------- kernel 2: means, valid, nv, loss_dis + 0.001*loss_reg ----------
// One block per image (was 1 block total, serial over images).
__global__ __launch_bounds__(256) void k_stats(const float* __restrict__ sums,
                                               const float* __restrict__ counts,
                                               float* __restrict__ means,
                                               float* __restrict__ validf,
                                               float* __restrict__ nvArr,
                                               float* __restrict__ imgPart) {
  __shared__ float ml[KCLS*129];   // padded [k][c], stride 129 -> conflict-free
  __shared__ float sval[KCLS];
  __shared__ float red[256];
  __shared__ float nvs;
  const int tid = threadIdx.x;
  const int n = blockIdx.x;

  for (int i = tid; i < KCLS*CCH; i += 256) {
    const int k = i >> 7, c = i & 127;
    const float m = sums[n*KCLS*CCH + i] / fmaxf(counts[n*KCLS + k], 1.f);
    means[n*KCLS*CCH + i] = m;
    ml[k*129 + c] = m;
  }
  if (tid < KCLS) {
    const float v = (counts[n*KCLS + tid] > 20.f) ? 1.f : 0.f;
    sval[tid] = v;
    validf[n*KCLS + tid] = v;
  }
  __syncthreads();
  if (tid == 0) {
    float s = 0.f;
    for (int k = 0; k < KCLS; ++k) s += sval[k];
    nvs = fmaxf(s, 1.f);
    nvArr[n] = nvs;
  }
  __syncthreads();

  // loss_dis: ordered pairs f != s, both valid
  float local = 0.f;
  for (int pr = tid; pr < KCLS*KCLS; pr += 256) {
    const int f = pr / KCLS, s2 = pr % KCLS;
    if (f != s2 && sval[f] > 0.f && sval[s2] > 0.f) {
      float acc = 0.f;
      for (int c = 0; c < CCH; ++c) {
        const float d = ml[f*129 + c] - ml[s2*129 + c];
        acc = fmaf(d, d, acc);
      }
      const float t = fmaxf(3.0f - sqrtf(acc), 0.f);   // 2*DELTA = 3
      local += t * t;
    }
  }
  // loss_reg: center norms of valid classes
  float localReg = 0.f;
  if (tid < KCLS && sval[tid] > 0.f) {
    float acc = 0.f;
    for (int c = 0; c < CCH; ++c) {
      const float m = ml[tid*129 + c];
      acc = fmaf(m, m, acc);
    }
    localReg = sqrtf(acc);
  }
  red[tid] = local;
  __syncthreads();
  for (int s3 = 128; s3 >= 1; s3 >>= 1) {
    if (tid < s3) red[tid] += red[tid + s3];
    __syncthreads();
  }
  const float disSum = red[0];
  __syncthreads();
  red[tid] = localReg;
  __syncthreads();
  for (int s3 = 128; s3 >= 1; s3 >>= 1) {
    if (tid < s3) red[tid] += red[tid + s3];
    __syncthreads();
  }
  if (tid == 0) {
    const float nv = nvs;
    const float dis = disSum / fmaxf(nv*(nv - 1.f), 1.f);
    const float reg = red[0] / nv;
    imgPart[n] = dis + 0.001f * reg;
  }
}

// ---------- kernel 3: loss_var pass (second full read of predict) ----------
// thread = 4 consecutive pixels; c-loop reads lane-contiguous float4.
// means transposed in LDS as [c][k] stride 20: per-c class-indexed reads
// hit 19 distinct banks (same-u lanes broadcast) -> conflict-free.
__global__ __launch_bounds__(256) void k_var(const float* __restrict__ predict,
                                             const int* __restrict__ target,
                                             const float* __restrict__ means,
                                             float* __restrict__ per_cls) {
  __shared__ float mT[CCH*20];   // 10240 B
  __shared__ float pc[KCLS];
  const int tid = threadIdx.x;
  const int n = blockIdx.x >> 7;
  const int tile = blockIdx.x & 127;

  for (int i = tid; i < KCLS*CCH; i += 256) {
    const int k = i >> 7, c = i & 127;
    mT[c*20 + k] = means[n*KCLS*CCH + i];
  }
  if (tid < KCLS) pc[tid] = 0.f;

  const int p0 = tile*1024 + tid*4;
  const int4 lb = *(const int4*)(target + (size_t)n*PPIX + p0);
  const unsigned u0 = min((unsigned)lb.x, (unsigned)(KCLS-1));
  const unsigned u1 = min((unsigned)lb.y, (unsigned)(KCLS-1));
  const unsigned u2 = min((unsigned)lb.z, (unsigned)(KCLS-1));
  const unsigned u3 = min((unsigned)lb.w, (unsigned)(KCLS-1));
  __syncthreads();

  float acc0 = 0.f, acc1 = 0.f, acc2 = 0.f, acc3 = 0.f;
  const float* gp = predict + (size_t)n*CCH*PPIX + p0;
#pragma unroll 8
  for (int c = 0; c < CCH; ++c) {
    const float4 v = *(const float4*)gp;
    gp += PPIX;
    const float* row = mT + c*20;
    const float d0 = row[u0] - v.x; acc0 = fmaf(d0, d0, acc0);
    const float d1 = row[u1] - v.y; acc1 = fmaf(d1, d1, acc1);
    const float d2 = row[u2] - v.z; acc2 = fmaf(d2, d2, acc2);
    const float d3 = row[u3] - v.w; acc3 = fmaf(d3, d3, acc3);
  }
  {
    float t;
    t = fmaxf(sqrtf(acc0) - 0.5f, 0.f); if ((unsigned)lb.x < KCLS) atomicAdd(&pc[lb.x], t*t);
    t = fmaxf(sqrtf(acc1) - 0.5f, 0.f); if ((unsigned)lb.y < KCLS) atomicAdd(&pc[lb.y], t*t);
    t = fmaxf(sqrtf(acc2) - 0.5f, 0.f); if ((unsigned)lb.z < KCLS) atomicAdd(&pc[lb.z], t*t);
    t = fmaxf(sqrtf(acc3) - 0.5f, 0.f); if ((unsigned)lb.w < KCLS) atomicAdd(&pc[lb.w], t*t);
  }
  __syncthreads();
  if (tid < KCLS) atomicAdd(&per_cls[n*KCLS + tid], pc[tid]);
}

// ---------- kernel 4: combine ----------
__global__ __launch_bounds__(128) void k_final(const float* __restrict__ per_cls,
                                               const float* __restrict__ counts,
                                               const float* __restrict__ validf,
                                               const float* __restrict__ nvArr,
                                               const float* __restrict__ imgPart,
                                               float* __restrict__ out) {
  __shared__ float red[128];
  const int tid = threadIdx.x;
  float local = 0.f;
  if (tid < NIMG*KCLS) {
    const int n = tid / KCLS;
    local = validf[tid] * (per_cls[tid] / fmaxf(counts[tid], 1.f)) / nvArr[n];
  } else if (tid < NIMG*KCLS + NIMG) {
    local = imgPart[tid - NIMG*KCLS];
  }
  red[tid] = local;
  __syncthreads();
  for (int s = 64; s >= 1; s >>= 1) {
    if (tid < s) red[tid] += red[tid + s];
    __syncthreads();
  }
  if (tid == 0) out[0] = 0.25f * red[0];   // mean over NIMG=4
}

extern "C" void kernel_launch(void* const* d_in, const int* in_sizes, int n_in,
                              void* d_out, int out_size, void* d_ws, size_t ws_size,
                              hipStream_t stream) {
  const float* predict = (const float*)d_in[0];
  const int*   target  = (const int*)d_in[1];
  float* out = (float*)d_out;
  float* ws  = (float*)d_ws;

  float* sums    = ws;            // 9728
  float* counts  = ws + 9728;     // 76
  float* per_cls = ws + 9804;     // 76
  float* means   = ws + 9880;     // 9728
  float* validf  = ws + 19608;    // 76
  float* nvArr   = ws + 19684;    // 4
  float* imgPart = ws + 19688;    // 4

  // zero accumulators (sums + counts + per_cls); ws is poisoned 0xAA
  hipMemsetAsync(ws, 0, (size_t)9880 * sizeof(float), stream);

  k_sums <<<NIMG*128, 256, 0, stream>>>(predict, target, sums, counts);
  k_stats<<<NIMG, 256, 0, stream>>>(sums, counts, means, validf, nvArr, imgPart);
  k_var  <<<NIMG*128, 256, 0, stream>>>(predict, target, means, per_cls);
  k_final<<<1, 128, 0, stream>>>(per_cls, counts, validf, nvArr, imgPart, out);
}